// Round 5
// baseline (253.838 us; speedup 1.0000x reference)
//
#include <hip/hip_runtime.h>

#define SEQ 4096
#define EMB 1024
#define HS 64

typedef __attribute__((ext_vector_type(8))) short bf16x8;
typedef __attribute__((ext_vector_type(4))) float f32x4;

__device__ __forceinline__ unsigned short f2b(float f) {
    union { float f; unsigned u; } v; v.f = f;
    unsigned r = v.u + 0x7fffu + ((v.u >> 16) & 1u);
    return (unsigned short)(r >> 16);
}

// ---------- W transpose + cast: Wt[192][1024] bf16; rows 0-63=Q (pre-scaled), 64-127=K, 128-191=V
__global__ __launch_bounds__(256) void wt_kernel(const float* __restrict__ Wq,
                                                 const float* __restrict__ Wk,
                                                 const float* __restrict__ Wv,
                                                 unsigned short* __restrict__ Wt) {
    int id = blockIdx.x * 256 + threadIdx.x;
    int mat = id >> 16;
    int rem = id & 65535;
    int k = rem >> 6;
    int n = rem & 63;
    const float* W = (mat == 0) ? Wq : (mat == 1) ? Wk : Wv;
    float scale = (mat == 0) ? 0.125f * 1.44269504f : 1.0f;   // fold 1/sqrt(64) * log2(e) into Q
    Wt[(mat * HS + n) * EMB + k] = f2b(W[k * HS + n] * scale);
}

// ---------- fused QKV projection: 4 waves/block share 16 rows; wave w -> output cols 48w..48w+47
__global__ __launch_bounds__(256, 4) void proj_kernel(const float* __restrict__ x,
                                                      const unsigned short* __restrict__ Wt,
                                                      unsigned short* __restrict__ Qb,
                                                      unsigned short* __restrict__ Kb,
                                                      unsigned short* __restrict__ Vt) {
    const int tid = threadIdx.x;
    const int wave = tid >> 6, lane = tid & 63;
    const int col = lane & 15, quad = lane >> 4;
    const int m0 = blockIdx.x * 16;
    const int b = m0 >> 12, t0 = m0 & 4095;

    f32x4 acc[3];
    #pragma unroll
    for (int j = 0; j < 3; j++) acc[j] = (f32x4){0.f, 0.f, 0.f, 0.f};

    const float* xp = x + (size_t)(m0 + col) * EMB + quad * 8;
    float4 nxt0 = *(const float4*)(xp + 0);
    float4 nxt1 = *(const float4*)(xp + 4);
    float4 nxt2 = *(const float4*)(xp + 32);
    float4 nxt3 = *(const float4*)(xp + 36);

    for (int k0 = 0; k0 < EMB; k0 += 64) {
        float4 c0 = nxt0, c1 = nxt1, c2 = nxt2, c3 = nxt3;
        if (k0 + 64 < EMB) {
            nxt0 = *(const float4*)(xp + k0 + 64);
            nxt1 = *(const float4*)(xp + k0 + 68);
            nxt2 = *(const float4*)(xp + k0 + 96);
            nxt3 = *(const float4*)(xp + k0 + 100);
        }
        bf16x8 bfr[3][2];
        #pragma unroll
        for (int j = 0; j < 3; j++) {
            const unsigned short* wp = Wt + (size_t)((wave * 3 + j) * 16 + col) * EMB + k0 + quad * 8;
            bfr[j][0] = *(const bf16x8*)(wp);
            bfr[j][1] = *(const bf16x8*)(wp + 32);
        }
        bf16x8 af[2];
        af[0][0] = (short)f2b(c0.x); af[0][1] = (short)f2b(c0.y);
        af[0][2] = (short)f2b(c0.z); af[0][3] = (short)f2b(c0.w);
        af[0][4] = (short)f2b(c1.x); af[0][5] = (short)f2b(c1.y);
        af[0][6] = (short)f2b(c1.z); af[0][7] = (short)f2b(c1.w);
        af[1][0] = (short)f2b(c2.x); af[1][1] = (short)f2b(c2.y);
        af[1][2] = (short)f2b(c2.z); af[1][3] = (short)f2b(c2.w);
        af[1][4] = (short)f2b(c3.x); af[1][5] = (short)f2b(c3.y);
        af[1][6] = (short)f2b(c3.z); af[1][7] = (short)f2b(c3.w);
        #pragma unroll
        for (int j = 0; j < 3; j++)
            #pragma unroll
            for (int c = 0; c < 2; c++)
                acc[j] = __builtin_amdgcn_mfma_f32_16x16x32_bf16(af[c], bfr[j][c], acc[j], 0, 0, 0);
    }
    #pragma unroll
    for (int j = 0; j < 3; j++) {
        const int g = wave * 3 + j;            // 0..11
        const int mat = g >> 2;                // 0=Q 1=K 2=V (wave-uniform)
        const int ncol = (g & 3) * 16 + col;
        #pragma unroll
        for (int r = 0; r < 4; r++) {
            unsigned short val = f2b(acc[j][r]);
            int row16 = quad * 4 + r;
            if (mat == 0)      Qb[(size_t)(m0 + row16) * HS + ncol] = val;
            else if (mat == 1) Kb[(size_t)(m0 + row16) * HS + ncol] = val;
            else               Vt[((size_t)b * HS + ncol) * SEQ + t0 + row16] = val;
        }
    }
}

// ---------- flash attention (causal), split-KV x4, one wave per (tile, split), K-prefetch pipeline
__global__ __launch_bounds__(64, 4) void attn_kernel(const unsigned short* __restrict__ Qb,
                                                     const unsigned short* __restrict__ Kb,
                                                     const unsigned short* __restrict__ Vt,
                                                     float* __restrict__ Opart,
                                                     float* __restrict__ Lpart) {
    __shared__ unsigned short P_lds[16 * 72];
    const int lane = threadIdx.x;
    const int col = lane & 15, quad = lane >> 4;
    const int bid = blockIdx.x;            // 4096
    const int split = bid & 3;
    const int b = (bid >> 2) & 3;
    const int tile = 255 - (bid >> 4);     // longest-first
    const int q0 = tile * 16;
    const size_t qrow = (size_t)(b << 12) + q0;

    const int ns = (q0 + 79) >> 6;         // KV blocks covering [0, q0+16)
    const int s_beg = (ns * split) >> 2;
    const int s_end = (ns * (split + 1)) >> 2;

    bf16x8 qf[2];
    #pragma unroll
    for (int c = 0; c < 2; c++)
        qf[c] = *(const bf16x8*)(Qb + (qrow + col) * HS + quad * 8 + c * 32);

    f32x4 o[4];
    float l[4];
    #pragma unroll
    for (int ct = 0; ct < 4; ct++) o[ct] = (f32x4){0.f, 0.f, 0.f, 0.f};
    #pragma unroll
    for (int r = 0; r < 4; r++) l[r] = 0.f;

    const unsigned short* Kp = Kb + ((size_t)(b << 12)) * HS;
    const unsigned short* Vp = Vt + (size_t)b * HS * SEQ;

    if (s_beg < s_end) {
        bf16x8 kf[4][2];
        #pragma unroll
        for (int ct = 0; ct < 4; ct++) {
            const unsigned short* kp = Kp + (size_t)((s_beg << 6) + ct * 16 + col) * HS + quad * 8;
            kf[ct][0] = *(const bf16x8*)(kp);
            kf[ct][1] = *(const bf16x8*)(kp + 32);
        }
        for (int s = s_beg; s < s_end; s++) {
            const int kv0 = s << 6;
            f32x4 sacc[4];
            #pragma unroll
            for (int ct = 0; ct < 4; ct++) sacc[ct] = (f32x4){0.f, 0.f, 0.f, 0.f};
            #pragma unroll
            for (int ct = 0; ct < 4; ct++)
                #pragma unroll
                for (int c = 0; c < 2; c++)
                    sacc[ct] = __builtin_amdgcn_mfma_f32_16x16x32_bf16(qf[c], kf[ct][c], sacc[ct], 0, 0, 0);

            // V loads for this step + K prefetch for next step, issued before softmax VALU
            bf16x8 vf[4][2];
            #pragma unroll
            for (int ct = 0; ct < 4; ct++) {
                const unsigned short* vp = Vp + (size_t)(ct * 16 + col) * SEQ + kv0 + quad * 8;
                vf[ct][0] = *(const bf16x8*)(vp);
                vf[ct][1] = *(const bf16x8*)(vp + 32);
            }
            if (s + 1 < s_end) {
                #pragma unroll
                for (int ct = 0; ct < 4; ct++) {
                    const unsigned short* kp = Kp + (size_t)(((s + 1) << 6) + ct * 16 + col) * HS + quad * 8;
                    kf[ct][0] = *(const bf16x8*)(kp);
                    kf[ct][1] = *(const bf16x8*)(kp + 32);
                }
            }

            // max-free softmax: p = 2^s (scale folded into Q)
            const bool lastT = (s == ns - 1);
            float p[4][4], rsum[4];
            #pragma unroll
            for (int r = 0; r < 4; r++) rsum[r] = 0.f;
            #pragma unroll
            for (int ct = 0; ct < 4; ct++) {
                int cg = kv0 + ct * 16 + col;
                #pragma unroll
                for (int r = 0; r < 4; r++) {
                    int rg = q0 + quad * 4 + r;
                    float e = __builtin_exp2f(sacc[ct][r]);
                    p[ct][r] = (lastT && cg > rg) ? 0.f : e;
                    rsum[r] += p[ct][r];
                }
            }
            #pragma unroll
            for (int off = 1; off < 16; off <<= 1)
                #pragma unroll
                for (int r = 0; r < 4; r++)
                    rsum[r] += __shfl_xor(rsum[r], off, 64);
            #pragma unroll
            for (int r = 0; r < 4; r++) l[r] += rsum[r];

            // P: C-layout -> wave-private LDS -> A-layout
            #pragma unroll
            for (int ct = 0; ct < 4; ct++)
                #pragma unroll
                for (int r = 0; r < 4; r++)
                    P_lds[(quad * 4 + r) * 72 + ct * 16 + col] = f2b(p[ct][r]);
            bf16x8 pf[2];
            #pragma unroll
            for (int c = 0; c < 2; c++)
                pf[c] = *(const bf16x8*)&P_lds[col * 72 + quad * 8 + c * 32];

            #pragma unroll
            for (int ct = 0; ct < 4; ct++)
                #pragma unroll
                for (int c = 0; c < 2; c++)
                    o[ct] = __builtin_amdgcn_mfma_f32_16x16x32_bf16(pf[c], vf[ct][c], o[ct], 0, 0, 0);
        }
    }

    const int idx = (((b << 8) + tile) << 2) + split;
    float* Op = Opart + (size_t)idx * 1024;
    #pragma unroll
    for (int ct = 0; ct < 4; ct++)
        #pragma unroll
        for (int r = 0; r < 4; r++)
            Op[(quad * 4 + r) * 64 + ct * 16 + col] = o[ct][r];
    if (col == 0) {
        #pragma unroll
        for (int r = 0; r < 4; r++)
            Lpart[idx * 16 + quad * 4 + r] = l[r];
    }
}

// ---------- combine split-KV partials ----------
__global__ __launch_bounds__(256) void comb_kernel(const float* __restrict__ Opart,
                                                   const float* __restrict__ Lpart,
                                                   float* __restrict__ out) {
    int gid = blockIdx.x * 256 + threadIdx.x;   // 262144
    int row = gid >> 4;                          // 0..16383
    int c4 = (gid & 15) * 4;
    int t = row & 4095;
    int tile = t >> 4, rin = t & 15;
    int tIdx = ((row >> 12) << 8) + tile;

    float4 acc = make_float4(0.f, 0.f, 0.f, 0.f);
    float l = 0.f;
    #pragma unroll
    for (int s = 0; s < 4; s++) {
        int idx = (tIdx << 2) + s;
        float4 v = *(const float4*)(Opart + (size_t)idx * 1024 + rin * 64 + c4);
        acc.x += v.x; acc.y += v.y; acc.z += v.z; acc.w += v.w;
        l += Lpart[idx * 16 + rin];
    }
    float inv = 1.f / l;
    float4 res = make_float4(acc.x * inv, acc.y * inv, acc.z * inv, acc.w * inv);
    *(float4*)(out + (size_t)row * HS + c4) = res;
}

extern "C" void kernel_launch(void* const* d_in, const int* in_sizes, int n_in,
                              void* d_out, int out_size, void* d_ws, size_t ws_size,
                              hipStream_t stream) {
    const float* x  = (const float*)d_in[0];
    const float* Wk = (const float*)d_in[1];
    const float* Wq = (const float*)d_in[2];
    const float* Wv = (const float*)d_in[3];
    float* out = (float*)d_out;

    char* ws = (char*)d_ws;
    unsigned short* Wt = (unsigned short*)(ws);                 // 393216 B
    unsigned short* Qb = (unsigned short*)(ws + 393216);        // 2 MiB
    unsigned short* Kb = (unsigned short*)(ws + 2490368);       // 2 MiB
    unsigned short* Vt = (unsigned short*)(ws + 4587520);       // 2 MiB
    float* Opart       = (float*)(ws + 6684672);                // 16.78 MB
    float* Lpart       = (float*)(ws + 23461888);               // 256 KB

    wt_kernel<<<dim3(768), dim3(256), 0, stream>>>(Wq, Wk, Wv, Wt);
    proj_kernel<<<dim3(1024), dim3(256), 0, stream>>>(x, Wt, Qb, Kb, Vt);
    attn_kernel<<<dim3(4096), dim3(64), 0, stream>>>(Qb, Kb, Vt, Opart, Lpart);
    comb_kernel<<<dim3(1024), dim3(256), 0, stream>>>(Opart, Lpart, out);
}

// Round 6
// 233.356 us; speedup vs baseline: 1.0878x; 1.0878x over previous
//
#include <hip/hip_runtime.h>

#define SEQ 4096
#define EMB 1024
#define HS 64

typedef __attribute__((ext_vector_type(8))) short bf16x8;
typedef __attribute__((ext_vector_type(4))) float f32x4;

__device__ __forceinline__ unsigned short f2b(float f) {
    union { float f; unsigned u; } v; v.f = f;
    unsigned r = v.u + 0x7fffu + ((v.u >> 16) & 1u);
    return (unsigned short)(r >> 16);
}

// ---------- W transpose + cast: Wt[192][1024] bf16; rows 0-63=Q (pre-scaled), 64-127=K, 128-191=V
__global__ __launch_bounds__(256) void wt_kernel(const float* __restrict__ Wq,
                                                 const float* __restrict__ Wk,
                                                 const float* __restrict__ Wv,
                                                 unsigned short* __restrict__ Wt) {
    int id = blockIdx.x * 256 + threadIdx.x;
    int mat = id >> 16;
    int rem = id & 65535;
    int k = rem >> 6;
    int n = rem & 63;
    const float* W = (mat == 0) ? Wq : (mat == 1) ? Wk : Wv;
    float scale = (mat == 0) ? 0.125f * 1.44269504f : 1.0f;   // fold 1/sqrt(64) * log2(e) into Q
    Wt[(mat * HS + n) * EMB + k] = f2b(W[k * HS + n] * scale);
}

// ---------- fused QKV projection: 4 waves/block share 16 rows; wave w -> output cols 48w..48w+47
__device__ __forceinline__ void ld_w(bf16x8 b[3][2], const unsigned short* Wt,
                                     int wave, int col, int quad, int k0) {
    #pragma unroll
    for (int j = 0; j < 3; j++) {
        const unsigned short* wp = Wt + (size_t)((wave * 3 + j) * 16 + col) * EMB + k0 + quad * 8;
        b[j][0] = *(const bf16x8*)(wp);
        b[j][1] = *(const bf16x8*)(wp + 32);
    }
}
__device__ __forceinline__ void ld_x(float4 xr[4], const float* xp, int k0) {
    xr[0] = *(const float4*)(xp + k0 + 0);
    xr[1] = *(const float4*)(xp + k0 + 4);
    xr[2] = *(const float4*)(xp + k0 + 32);
    xr[3] = *(const float4*)(xp + k0 + 36);
}
__device__ __forceinline__ void mk_af(bf16x8 af[2], const float4 xr[4]) {
    af[0][0] = (short)f2b(xr[0].x); af[0][1] = (short)f2b(xr[0].y);
    af[0][2] = (short)f2b(xr[0].z); af[0][3] = (short)f2b(xr[0].w);
    af[0][4] = (short)f2b(xr[1].x); af[0][5] = (short)f2b(xr[1].y);
    af[0][6] = (short)f2b(xr[1].z); af[0][7] = (short)f2b(xr[1].w);
    af[1][0] = (short)f2b(xr[2].x); af[1][1] = (short)f2b(xr[2].y);
    af[1][2] = (short)f2b(xr[2].z); af[1][3] = (short)f2b(xr[2].w);
    af[1][4] = (short)f2b(xr[3].x); af[1][5] = (short)f2b(xr[3].y);
    af[1][6] = (short)f2b(xr[3].z); af[1][7] = (short)f2b(xr[3].w);
}

__global__ __launch_bounds__(256, 4) void proj_kernel(const float* __restrict__ x,
                                                      const unsigned short* __restrict__ Wt,
                                                      unsigned short* __restrict__ Qb,
                                                      unsigned short* __restrict__ Kb,
                                                      unsigned short* __restrict__ Vt) {
    const int tid = threadIdx.x;
    const int wave = tid >> 6, lane = tid & 63;
    const int col = lane & 15, quad = lane >> 4;
    const int m0 = blockIdx.x * 16;
    const int b = m0 >> 12, t0 = m0 & 4095;

    f32x4 acc[3];
    #pragma unroll
    for (int j = 0; j < 3; j++) acc[j] = (f32x4){0.f, 0.f, 0.f, 0.f};

    const float* xp = x + (size_t)(m0 + col) * EMB + quad * 8;

    bf16x8 b0[3][2], b1[3][2];
    float4 x0[4], x1[4];
    ld_w(b0, Wt, wave, col, quad, 0);
    ld_x(x0, xp, 0);

    // 16 k-steps, unrolled x2 with double-buffered Wt/x
    #pragma unroll 1
    for (int k0 = 0; k0 < EMB; k0 += 128) {
        ld_w(b1, Wt, wave, col, quad, k0 + 64);
        ld_x(x1, xp, k0 + 64);
        {
            bf16x8 af[2];
            mk_af(af, x0);
            #pragma unroll
            for (int j = 0; j < 3; j++)
                #pragma unroll
                for (int c = 0; c < 2; c++)
                    acc[j] = __builtin_amdgcn_mfma_f32_16x16x32_bf16(af[c], b0[j][c], acc[j], 0, 0, 0);
        }
        if (k0 + 128 < EMB) {
            ld_w(b0, Wt, wave, col, quad, k0 + 128);
            ld_x(x0, xp, k0 + 128);
        }
        {
            bf16x8 af[2];
            mk_af(af, x1);
            #pragma unroll
            for (int j = 0; j < 3; j++)
                #pragma unroll
                for (int c = 0; c < 2; c++)
                    acc[j] = __builtin_amdgcn_mfma_f32_16x16x32_bf16(af[c], b1[j][c], acc[j], 0, 0, 0);
        }
    }
    #pragma unroll
    for (int j = 0; j < 3; j++) {
        const int g = wave * 3 + j;            // 0..11
        const int mat = g >> 2;                // 0=Q 1=K 2=V (wave-uniform)
        const int ncol = (g & 3) * 16 + col;
        #pragma unroll
        for (int r = 0; r < 4; r++) {
            unsigned short val = f2b(acc[j][r]);
            int row16 = quad * 4 + r;
            if (mat == 0)      Qb[(size_t)(m0 + row16) * HS + ncol] = val;
            else if (mat == 1) Kb[(size_t)(m0 + row16) * HS + ncol] = val;
            else               Vt[((size_t)b * HS + ncol) * SEQ + t0 + row16] = val;
        }
    }
}

// ---------- flash attention step (templated on causal-mask need) ----------
template<bool MASK>
__device__ __forceinline__ void attn_step(int s, int s_end, int ns, int q0,
                                          int col, int quad,
                                          const unsigned short* Kp,
                                          const unsigned short* Vp,
                                          const bf16x8 qf[2],
                                          bf16x8 kf[4][2],
                                          f32x4 o[4], float l[4],
                                          unsigned short* P_lds) {
    const int kv0 = s << 6;
    f32x4 sacc[4];
    #pragma unroll
    for (int ct = 0; ct < 4; ct++) sacc[ct] = (f32x4){0.f, 0.f, 0.f, 0.f};
    #pragma unroll
    for (int ct = 0; ct < 4; ct++)
        #pragma unroll
        for (int c = 0; c < 2; c++)
            sacc[ct] = __builtin_amdgcn_mfma_f32_16x16x32_bf16(qf[c], kf[ct][c], sacc[ct], 0, 0, 0);

    // V loads for this step + K prefetch for the next, issued before softmax VALU
    bf16x8 vf[4][2];
    #pragma unroll
    for (int ct = 0; ct < 4; ct++) {
        const unsigned short* vp = Vp + (size_t)(ct * 16 + col) * SEQ + kv0 + quad * 8;
        vf[ct][0] = *(const bf16x8*)(vp);
        vf[ct][1] = *(const bf16x8*)(vp + 32);
    }
    if (s + 1 < s_end) {
        #pragma unroll
        for (int ct = 0; ct < 4; ct++) {
            const unsigned short* kp = Kp + (size_t)(((s + 1) << 6) + ct * 16 + col) * HS + quad * 8;
            kf[ct][0] = *(const bf16x8*)(kp);
            kf[ct][1] = *(const bf16x8*)(kp + 32);
        }
    }

    // max-free softmax: p = 2^s (scale folded into Q); l accumulated PER-LANE only
    float p[4][4];
    #pragma unroll
    for (int ct = 0; ct < 4; ct++) {
        int cg = kv0 + ct * 16 + col;
        #pragma unroll
        for (int r = 0; r < 4; r++) {
            float e = __builtin_exp2f(sacc[ct][r]);
            if (MASK) {
                int rg = q0 + quad * 4 + r;
                e = (cg > rg) ? 0.f : e;
            }
            p[ct][r] = e;
            l[r] += e;
        }
    }

    // P: C-layout -> wave-private LDS -> A-layout
    #pragma unroll
    for (int ct = 0; ct < 4; ct++)
        #pragma unroll
        for (int r = 0; r < 4; r++)
            P_lds[(quad * 4 + r) * 72 + ct * 16 + col] = f2b(p[ct][r]);
    bf16x8 pf[2];
    #pragma unroll
    for (int c = 0; c < 2; c++)
        pf[c] = *(const bf16x8*)&P_lds[col * 72 + quad * 8 + c * 32];

    #pragma unroll
    for (int ct = 0; ct < 4; ct++)
        #pragma unroll
        for (int c = 0; c < 2; c++)
            o[ct] = __builtin_amdgcn_mfma_f32_16x16x32_bf16(pf[c], vf[ct][c], o[ct], 0, 0, 0);
}

// ---------- flash attention (causal), split-KV x4, one wave per (tile, split) ----------
__global__ __launch_bounds__(64, 4) void attn_kernel(const unsigned short* __restrict__ Qb,
                                                     const unsigned short* __restrict__ Kb,
                                                     const unsigned short* __restrict__ Vt,
                                                     float* __restrict__ Opart,
                                                     float* __restrict__ Lpart) {
    __shared__ unsigned short P_lds[16 * 72];
    const int lane = threadIdx.x;
    const int col = lane & 15, quad = lane >> 4;
    const int bid = blockIdx.x;            // 4096
    const int split = bid & 3;
    const int b = (bid >> 2) & 3;
    const int tile = 255 - (bid >> 4);     // longest-first
    const int q0 = tile * 16;
    const size_t qrow = (size_t)(b << 12) + q0;

    const int ns = (q0 + 79) >> 6;         // KV blocks covering [0, q0+16)
    const int s_beg = (ns * split) >> 2;
    const int s_end = (ns * (split + 1)) >> 2;

    bf16x8 qf[2];
    #pragma unroll
    for (int c = 0; c < 2; c++)
        qf[c] = *(const bf16x8*)(Qb + (qrow + col) * HS + quad * 8 + c * 32);

    f32x4 o[4];
    float l[4];
    #pragma unroll
    for (int ct = 0; ct < 4; ct++) o[ct] = (f32x4){0.f, 0.f, 0.f, 0.f};
    #pragma unroll
    for (int r = 0; r < 4; r++) l[r] = 0.f;

    const unsigned short* Kp = Kb + ((size_t)(b << 12)) * HS;
    const unsigned short* Vp = Vt + (size_t)b * HS * SEQ;

    if (s_beg < s_end) {
        bf16x8 kf[4][2];
        #pragma unroll
        for (int ct = 0; ct < 4; ct++) {
            const unsigned short* kp = Kp + (size_t)((s_beg << 6) + ct * 16 + col) * HS + quad * 8;
            kf[ct][0] = *(const bf16x8*)(kp);
            kf[ct][1] = *(const bf16x8*)(kp + 32);
        }
        const int hot_end = (s_end == ns) ? ns - 1 : s_end;
        for (int s = s_beg; s < hot_end; s++)
            attn_step<false>(s, s_end, ns, q0, col, quad, Kp, Vp, qf, kf, o, l, P_lds);
        if (s_end == ns)
            attn_step<true>(ns - 1, s_end, ns, q0, col, quad, Kp, Vp, qf, kf, o, l, P_lds);
    }

    // deferred cross-lane row-sum: one butterfly after the loop
    #pragma unroll
    for (int off = 1; off < 16; off <<= 1)
        #pragma unroll
        for (int r = 0; r < 4; r++)
            l[r] += __shfl_xor(l[r], off, 64);

    // partials: contiguous 1KB-per-instruction stores. Layout: Opart[idx][ct][lane] (f32x4)
    const int idx = (((b << 8) + tile) << 2) + split;
    float* Op = Opart + (size_t)idx * 1024;
    #pragma unroll
    for (int ct = 0; ct < 4; ct++)
        *(f32x4*)(Op + ct * 256 + lane * 4) = o[ct];
    if (col == 0) {
        #pragma unroll
        for (int r = 0; r < 4; r++)
            Lpart[idx * 16 + quad * 4 + r] = l[r];
    }
}

// ---------- combine split-KV partials ----------
__global__ __launch_bounds__(256) void comb_kernel(const float* __restrict__ Opart,
                                                   const float* __restrict__ Lpart,
                                                   float* __restrict__ out) {
    int gid = blockIdx.x * 256 + threadIdx.x;   // 262144
    int row = gid >> 4;                          // 0..16383
    int c4 = (gid & 15) * 4;
    int t = row & 4095;
    int tile = t >> 4, rin = t & 15;
    int tIdx = ((row >> 12) << 8) + tile;
    int quad = rin >> 2, r = rin & 3;
    int ct = c4 >> 4, col0 = c4 & 15;

    float acc[4] = {0.f, 0.f, 0.f, 0.f};
    float l = 0.f;
    #pragma unroll
    for (int s = 0; s < 4; s++) {
        int idx = (tIdx << 2) + s;
        const float* base = Opart + (size_t)idx * 1024 + ct * 256 + quad * 64 + r;
        #pragma unroll
        for (int j = 0; j < 4; j++) acc[j] += base[(col0 + j) * 4];
        l += Lpart[idx * 16 + rin];
    }
    float inv = 1.f / l;
    float4 res = make_float4(acc[0] * inv, acc[1] * inv, acc[2] * inv, acc[3] * inv);
    *(float4*)(out + (size_t)row * HS + c4) = res;
}

extern "C" void kernel_launch(void* const* d_in, const int* in_sizes, int n_in,
                              void* d_out, int out_size, void* d_ws, size_t ws_size,
                              hipStream_t stream) {
    const float* x  = (const float*)d_in[0];
    const float* Wk = (const float*)d_in[1];
    const float* Wq = (const float*)d_in[2];
    const float* Wv = (const float*)d_in[3];
    float* out = (float*)d_out;

    char* ws = (char*)d_ws;
    unsigned short* Wt = (unsigned short*)(ws);                 // 393216 B
    unsigned short* Qb = (unsigned short*)(ws + 393216);        // 2 MiB
    unsigned short* Kb = (unsigned short*)(ws + 2490368);       // 2 MiB
    unsigned short* Vt = (unsigned short*)(ws + 4587520);       // 2 MiB
    float* Opart       = (float*)(ws + 6684672);                // 16.78 MB
    float* Lpart       = (float*)(ws + 23461888);               // 256 KB

    wt_kernel<<<dim3(768), dim3(256), 0, stream>>>(Wq, Wk, Wv, Wt);
    proj_kernel<<<dim3(1024), dim3(256), 0, stream>>>(x, Wt, Qb, Kb, Vt);
    attn_kernel<<<dim3(4096), dim3(64), 0, stream>>>(Qb, Kb, Vt, Opart, Lpart);
    comb_kernel<<<dim3(1024), dim3(256), 0, stream>>>(Opart, Lpart, out);
}

// Round 7
// 185.321 us; speedup vs baseline: 1.3697x; 1.2592x over previous
//
#include <hip/hip_runtime.h>

#define SEQ 4096
#define EMB 1024
#define HS 64
#define PLDA 72   // padded LDS row (shorts): 64 bf16 + 8 pad, keeps 16B alignment

typedef __attribute__((ext_vector_type(8))) short bf16x8;
typedef __attribute__((ext_vector_type(4))) float f32x4;

__device__ __forceinline__ unsigned short f2b(float f) {
    union { float f; unsigned u; } v; v.f = f;
    unsigned r = v.u + 0x7fffu + ((v.u >> 16) & 1u);
    return (unsigned short)(r >> 16);
}

// ---------- W transpose + cast: Wt[192][1024] bf16; rows 0-63=Q (pre-scaled), 64-127=K, 128-191=V
__global__ __launch_bounds__(256) void wt_kernel(const float* __restrict__ Wq,
                                                 const float* __restrict__ Wk,
                                                 const float* __restrict__ Wv,
                                                 unsigned short* __restrict__ Wt) {
    int id = blockIdx.x * 256 + threadIdx.x;
    int mat = id >> 16;
    int rem = id & 65535;
    int k = rem >> 6;
    int n = rem & 63;
    const float* W = (mat == 0) ? Wq : (mat == 1) ? Wk : Wv;
    float scale = (mat == 0) ? 0.125f * 1.44269504f : 1.0f;   // fold 1/sqrt(64) * log2(e) into Q
    Wt[(mat * HS + n) * EMB + k] = f2b(W[k * HS + n] * scale);
}

// ---------- fused QKV projection: block GEMM, 64 rows x 192 cols, LDS-staged, reg-prefetch
__global__ __launch_bounds__(256, 2) void proj_kernel(const float* __restrict__ x,
                                                      const unsigned short* __restrict__ Wt,
                                                      unsigned short* __restrict__ Qb,
                                                      unsigned short* __restrict__ Kb,
                                                      unsigned short* __restrict__ Vt) {
    __shared__ unsigned short A_lds[64 * PLDA];    // 9216 B
    __shared__ unsigned short W_lds[192 * PLDA];   // 27648 B
    const int tid = threadIdx.x;
    const int wave = tid >> 6, lane = tid & 63;
    const int col = lane & 15, quad = lane >> 4;
    const int m0 = blockIdx.x * 64;
    const int b = m0 >> 12, t0 = m0 & 4095;

    // staging index maps (fully coalesced: full 64B lines)
    const int xrow = tid >> 4;          // 0..15 (+16 per round)
    const int xfc  = (tid & 15) * 4;    // float offset in k-tile
    const int wn   = tid >> 3;          // 0..31 (+32 per round)
    const int wcp  = (tid & 7) * 8;     // short offset in k-tile

    f32x4 acc[4][3];
    #pragma unroll
    for (int i = 0; i < 4; i++)
        #pragma unroll
        for (int j = 0; j < 3; j++) acc[i][j] = (f32x4){0.f, 0.f, 0.f, 0.f};

    float4 xr[4];
    bf16x8 wr[6];
    // preload k-tile 0
    #pragma unroll
    for (int i = 0; i < 4; i++)
        xr[i] = *(const float4*)(x + (size_t)(m0 + i * 16 + xrow) * EMB + xfc);
    #pragma unroll
    for (int i = 0; i < 6; i++)
        wr[i] = *(const bf16x8*)(Wt + (size_t)(i * 32 + wn) * EMB + wcp);

    #pragma unroll 1
    for (int k0 = 0; k0 < EMB; k0 += 64) {
        __syncthreads();   // previous iteration's readers done
        // write staged tile to LDS (convert x to bf16)
        #pragma unroll
        for (int i = 0; i < 4; i++) {
            ushort4 bb;
            bb.x = f2b(xr[i].x); bb.y = f2b(xr[i].y);
            bb.z = f2b(xr[i].z); bb.w = f2b(xr[i].w);
            *(ushort4*)&A_lds[(i * 16 + xrow) * PLDA + xfc] = bb;
        }
        #pragma unroll
        for (int i = 0; i < 6; i++)
            *(bf16x8*)&W_lds[(i * 32 + wn) * PLDA + wcp] = wr[i];
        __syncthreads();   // tile ready
        // prefetch next k-tile into registers (lands during compute below)
        if (k0 + 64 < EMB) {
            #pragma unroll
            for (int i = 0; i < 4; i++)
                xr[i] = *(const float4*)(x + (size_t)(m0 + i * 16 + xrow) * EMB + k0 + 64 + xfc);
            #pragma unroll
            for (int i = 0; i < 6; i++)
                wr[i] = *(const bf16x8*)(Wt + (size_t)(i * 32 + wn) * EMB + k0 + 64 + wcp);
        }
        // compute: fragments from LDS, 24 MFMA/wave
        #pragma unroll
        for (int kc = 0; kc < 2; kc++) {
            bf16x8 af[4], bfr[3];
            #pragma unroll
            for (int mt = 0; mt < 4; mt++)
                af[mt] = *(const bf16x8*)&A_lds[(mt * 16 + col) * PLDA + kc * 32 + quad * 8];
            #pragma unroll
            for (int nt = 0; nt < 3; nt++)
                bfr[nt] = *(const bf16x8*)&W_lds[(wave * 48 + nt * 16 + col) * PLDA + kc * 32 + quad * 8];
            #pragma unroll
            for (int mt = 0; mt < 4; mt++)
                #pragma unroll
                for (int nt = 0; nt < 3; nt++)
                    acc[mt][nt] = __builtin_amdgcn_mfma_f32_16x16x32_bf16(af[mt], bfr[nt], acc[mt][nt], 0, 0, 0);
        }
    }

    // epilogue: wave owns global col-group [wave*48, wave*48+48)
    #pragma unroll
    for (int mt = 0; mt < 4; mt++)
        #pragma unroll
        for (int nt = 0; nt < 3; nt++) {
            const int g = wave * 3 + nt;       // 0..11
            const int mat = g >> 2;            // 0=Q 1=K 2=V (wave-uniform)
            const int ncol = (g & 3) * 16 + col;
            #pragma unroll
            for (int r = 0; r < 4; r++) {
                unsigned short val = f2b(acc[mt][nt][r]);
                int row = mt * 16 + quad * 4 + r;
                if (mat == 0)      Qb[(size_t)(m0 + row) * HS + ncol] = val;
                else if (mat == 1) Kb[(size_t)(m0 + row) * HS + ncol] = val;
                else               Vt[((size_t)b * HS + ncol) * SEQ + t0 + row] = val;
            }
        }
}

// ---------- flash attention step (templated on causal-mask need) ----------
template<bool MASK>
__device__ __forceinline__ void attn_step(int s, int s_end, int ns, int q0,
                                          int col, int quad,
                                          const unsigned short* Kp,
                                          const unsigned short* Vp,
                                          const bf16x8 qf[2],
                                          bf16x8 kf[4][2],
                                          f32x4 o[4], float l[4],
                                          unsigned short* P_lds) {
    const int kv0 = s << 6;
    f32x4 sacc[4];
    #pragma unroll
    for (int ct = 0; ct < 4; ct++) sacc[ct] = (f32x4){0.f, 0.f, 0.f, 0.f};
    #pragma unroll
    for (int ct = 0; ct < 4; ct++)
        #pragma unroll
        for (int c = 0; c < 2; c++)
            sacc[ct] = __builtin_amdgcn_mfma_f32_16x16x32_bf16(qf[c], kf[ct][c], sacc[ct], 0, 0, 0);

    // V loads for this step + K prefetch for the next, issued before softmax VALU
    bf16x8 vf[4][2];
    #pragma unroll
    for (int ct = 0; ct < 4; ct++) {
        const unsigned short* vp = Vp + (size_t)(ct * 16 + col) * SEQ + kv0 + quad * 8;
        vf[ct][0] = *(const bf16x8*)(vp);
        vf[ct][1] = *(const bf16x8*)(vp + 32);
    }
    if (s + 1 < s_end) {
        #pragma unroll
        for (int ct = 0; ct < 4; ct++) {
            const unsigned short* kp = Kp + (size_t)(((s + 1) << 6) + ct * 16 + col) * HS + quad * 8;
            kf[ct][0] = *(const bf16x8*)(kp);
            kf[ct][1] = *(const bf16x8*)(kp + 32);
        }
    }

    // max-free softmax: p = 2^s (scale folded into Q); l accumulated PER-LANE only
    float p[4][4];
    #pragma unroll
    for (int ct = 0; ct < 4; ct++) {
        int cg = kv0 + ct * 16 + col;
        #pragma unroll
        for (int r = 0; r < 4; r++) {
            float e = __builtin_exp2f(sacc[ct][r]);
            if (MASK) {
                int rg = q0 + quad * 4 + r;
                e = (cg > rg) ? 0.f : e;
            }
            p[ct][r] = e;
            l[r] += e;
        }
    }

    // P: C-layout -> wave-private LDS -> A-layout
    #pragma unroll
    for (int ct = 0; ct < 4; ct++)
        #pragma unroll
        for (int r = 0; r < 4; r++)
            P_lds[(quad * 4 + r) * 72 + ct * 16 + col] = f2b(p[ct][r]);
    bf16x8 pf[2];
    #pragma unroll
    for (int c = 0; c < 2; c++)
        pf[c] = *(const bf16x8*)&P_lds[col * 72 + quad * 8 + c * 32];

    #pragma unroll
    for (int ct = 0; ct < 4; ct++)
        #pragma unroll
        for (int c = 0; c < 2; c++)
            o[ct] = __builtin_amdgcn_mfma_f32_16x16x32_bf16(pf[c], vf[ct][c], o[ct], 0, 0, 0);
}

// ---------- flash attention (causal), split-KV x4, one wave per (tile, split) ----------
__global__ __launch_bounds__(64, 4) void attn_kernel(const unsigned short* __restrict__ Qb,
                                                     const unsigned short* __restrict__ Kb,
                                                     const unsigned short* __restrict__ Vt,
                                                     float* __restrict__ Opart,
                                                     float* __restrict__ Lpart) {
    __shared__ unsigned short P_lds[16 * 72];
    const int lane = threadIdx.x;
    const int col = lane & 15, quad = lane >> 4;
    const int bid = blockIdx.x;            // 4096
    const int split = bid & 3;
    const int b = (bid >> 2) & 3;
    const int tile = 255 - (bid >> 4);     // longest-first
    const int q0 = tile * 16;
    const size_t qrow = (size_t)(b << 12) + q0;

    const int ns = (q0 + 79) >> 6;         // KV blocks covering [0, q0+16)
    const int s_beg = (ns * split) >> 2;
    const int s_end = (ns * (split + 1)) >> 2;

    bf16x8 qf[2];
    #pragma unroll
    for (int c = 0; c < 2; c++)
        qf[c] = *(const bf16x8*)(Qb + (qrow + col) * HS + quad * 8 + c * 32);

    f32x4 o[4];
    float l[4];
    #pragma unroll
    for (int ct = 0; ct < 4; ct++) o[ct] = (f32x4){0.f, 0.f, 0.f, 0.f};
    #pragma unroll
    for (int r = 0; r < 4; r++) l[r] = 0.f;

    const unsigned short* Kp = Kb + ((size_t)(b << 12)) * HS;
    const unsigned short* Vp = Vt + (size_t)b * HS * SEQ;

    if (s_beg < s_end) {
        bf16x8 kf[4][2];
        #pragma unroll
        for (int ct = 0; ct < 4; ct++) {
            const unsigned short* kp = Kp + (size_t)((s_beg << 6) + ct * 16 + col) * HS + quad * 8;
            kf[ct][0] = *(const bf16x8*)(kp);
            kf[ct][1] = *(const bf16x8*)(kp + 32);
        }
        const int hot_end = (s_end == ns) ? ns - 1 : s_end;
        for (int s = s_beg; s < hot_end; s++)
            attn_step<false>(s, s_end, ns, q0, col, quad, Kp, Vp, qf, kf, o, l, P_lds);
        if (s_end == ns)
            attn_step<true>(ns - 1, s_end, ns, q0, col, quad, Kp, Vp, qf, kf, o, l, P_lds);
    }

    // deferred cross-lane row-sum: one butterfly after the loop
    #pragma unroll
    for (int off = 1; off < 16; off <<= 1)
        #pragma unroll
        for (int r = 0; r < 4; r++)
            l[r] += __shfl_xor(l[r], off, 64);

    // partials: contiguous 1KB-per-instruction stores. Layout: Opart[idx][ct][lane] (f32x4)
    const int idx = (((b << 8) + tile) << 2) + split;
    float* Op = Opart + (size_t)idx * 1024;
    #pragma unroll
    for (int ct = 0; ct < 4; ct++)
        *(f32x4*)(Op + ct * 256 + lane * 4) = o[ct];
    if (col == 0) {
        #pragma unroll
        for (int r = 0; r < 4; r++)
            Lpart[idx * 16 + quad * 4 + r] = l[r];
    }
}

// ---------- combine split-KV partials ----------
__global__ __launch_bounds__(256) void comb_kernel(const float* __restrict__ Opart,
                                                   const float* __restrict__ Lpart,
                                                   float* __restrict__ out) {
    int gid = blockIdx.x * 256 + threadIdx.x;   // 262144
    int row = gid >> 4;                          // 0..16383
    int c4 = (gid & 15) * 4;
    int t = row & 4095;
    int tile = t >> 4, rin = t & 15;
    int tIdx = ((row >> 12) << 8) + tile;
    int quad = rin >> 2, r = rin & 3;
    int ct = c4 >> 4, col0 = c4 & 15;

    float acc[4] = {0.f, 0.f, 0.f, 0.f};
    float l = 0.f;
    #pragma unroll
    for (int s = 0; s < 4; s++) {
        int idx = (tIdx << 2) + s;
        const float* base = Opart + (size_t)idx * 1024 + ct * 256 + quad * 64 + r;
        #pragma unroll
        for (int j = 0; j < 4; j++) acc[j] += base[(col0 + j) * 4];
        l += Lpart[idx * 16 + rin];
    }
    float inv = 1.f / l;
    float4 res = make_float4(acc[0] * inv, acc[1] * inv, acc[2] * inv, acc[3] * inv);
    *(float4*)(out + (size_t)row * HS + c4) = res;
}

extern "C" void kernel_launch(void* const* d_in, const int* in_sizes, int n_in,
                              void* d_out, int out_size, void* d_ws, size_t ws_size,
                              hipStream_t stream) {
    const float* x  = (const float*)d_in[0];
    const float* Wk = (const float*)d_in[1];
    const float* Wq = (const float*)d_in[2];
    const float* Wv = (const float*)d_in[3];
    float* out = (float*)d_out;

    char* ws = (char*)d_ws;
    unsigned short* Wt = (unsigned short*)(ws);                 // 393216 B
    unsigned short* Qb = (unsigned short*)(ws + 393216);        // 2 MiB
    unsigned short* Kb = (unsigned short*)(ws + 2490368);       // 2 MiB
    unsigned short* Vt = (unsigned short*)(ws + 4587520);       // 2 MiB
    float* Opart       = (float*)(ws + 6684672);                // 16.78 MB
    float* Lpart       = (float*)(ws + 23461888);               // 256 KB

    wt_kernel<<<dim3(768), dim3(256), 0, stream>>>(Wq, Wk, Wv, Wt);
    proj_kernel<<<dim3(256), dim3(256), 0, stream>>>(x, Wt, Qb, Kb, Vt);
    attn_kernel<<<dim3(4096), dim3(64), 0, stream>>>(Qb, Kb, Vt, Opart, Lpart);
    comb_kernel<<<dim3(1024), dim3(256), 0, stream>>>(Opart, Lpart, out);
}